// Round 1
// baseline (63.682 us; speedup 1.0000x reference)
//
#include <hip/hip_runtime.h>
#include <math.h>

#define SEQ_LEN 1024
#define NCLASS 8
#define NLINES 256
#define ALPHA_C 0.01f
#define SPW 0.3f
#define BLOCK 1024
#define PACK 4096.0f   // cnt*4096 + tsum, both integers; exact below 2^24

// Kernel 1: one block per sequence (B=64), 1024 threads, 1 token/thread.
// Phase 1: wave-level SEGMENTED suffix-scan (lines sorted => equal-line runs
// contiguous); only run-head lanes issue LDS atomics, at distinct lines.
// Phase 2 (folded into per-token epilogue): 5-wide windowed sums read
// directly from the bins — same summation order as the staged version,
// so the result is bitwise identical, but one barrier + 3KiB LDS cheaper.
// Cross-block reduction moved to a stream-ordered second kernel: no
// agent-scope release/acquire protocol, no spin, blocks exit immediately.
__global__ __launch_bounds__(BLOCK) void fused_kernel(
    const float* __restrict__ pred,
    const float* __restrict__ target,
    const int* __restrict__ lines,
    float* __restrict__ partials,     // [nblocks] in d_ws
    float inv_total)
{
    __shared__ float binCT[NLINES];    // packed cnt*4096 + sum(target)
    __shared__ float binS[NLINES];     // class-summed sigmoid
    __shared__ float wavesum[BLOCK / 64];

    const int b = blockIdx.x;
    const int tid = threadIdx.x;
    const int lane = tid & 63;
    const int token = b * SEQ_LEN + tid;   // each wave holds 64 consecutive tokens

    // Issue global loads FIRST: the harness's 256MiB ws poison evicts all of
    // L3 every iteration, so these are ~900cy HBM-cold misses. Issuing them
    // before the LDS init + barrier hides that latency.
    const int l = lines[token];
    const float4 p0 = ((const float4*)pred)[token * 2];
    const float4 p1 = ((const float4*)pred)[token * 2 + 1];
    const float4 t0 = ((const float4*)target)[token * 2];
    const float4 t1 = ((const float4*)target)[token * 2 + 1];

    if (tid < NLINES) {
        binCT[tid] = 0.f;
        binS[tid] = 0.f;
    }
    __syncthreads();

    const float px[NCLASS] = {p0.x, p0.y, p0.z, p0.w, p1.x, p1.y, p1.z, p1.w};

    const float tsum = t0.x + t0.y + t0.z + t0.w + t1.x + t1.y + t1.z + t1.w;
    unsigned tmask = 0;                    // targets are exactly 0/1
    tmask |= (t0.x > 0.5f) ? 1u : 0u;
    tmask |= (t0.y > 0.5f) ? 2u : 0u;
    tmask |= (t0.z > 0.5f) ? 4u : 0u;
    tmask |= (t0.w > 0.5f) ? 8u : 0u;
    tmask |= (t1.x > 0.5f) ? 16u : 0u;
    tmask |= (t1.y > 0.5f) ? 32u : 0u;
    tmask |= (t1.z > 0.5f) ? 64u : 0u;
    tmask |= (t1.w > 0.5f) ? 128u : 0u;

    float sg[NCLASS];
    float sgsum = 0.f;
    #pragma unroll
    for (int c = 0; c < NCLASS; ++c) {
        const float e = __expf(-px[c]);
        const float s = 1.f / (1.f + e);
        sg[c] = s;
        sgsum += s;
    }

    // segmented suffix-scan over the wave; run's first lane gets the run total
    {
        float rp = PACK + tsum;            // cnt=1 packed with tsum
        float rs = sgsum;
        #pragma unroll
        for (int off = 1; off < 64; off <<= 1) {
            const int   ln = __shfl_down(l,  off, 64);
            const float ap = __shfl_down(rp, off, 64);
            const float as = __shfl_down(rs, off, 64);
            const bool same = (lane + off < 64) && (ln == l);
            if (same) { rp += ap; rs += as; }
        }
        const int lprev = __shfl_up(l, 1, 64);
        if ((lane == 0) || (lprev != l)) {
            atomicAdd(&binCT[l], rp);
            atomicAdd(&binS[l], rs);
        }
    }
    __syncthreads();

    // Per-token: 5-wide windowed sums over line values [l-2, l+2], read
    // straight from the bins (same add order as the staged phase-2 loop =>
    // bitwise-identical), then the focal loss.
    float lsum;
    {
        const int lo = (l - 2 < 0) ? 0 : l - 2;
        const int hi = (l + 2 > NLINES - 1) ? NLINES - 1 : l + 2;
        float cp = 0.f, ss = 0.f;
        for (int v = lo; v <= hi; ++v) {
            cp += binCT[v];
            ss += binS[v];
        }
        const float cnt = floorf(cp / PACK);
        const float wT  = cp - cnt * PACK;

        const float counts = cnt - 1.f;         // exclude self
        const float ntgt = wT - tsum;           // exclude self
        const bool cond = (counts > 0.f) && (ntgt > 0.f);
        const float pfac = cond ? (SPW * 0.1f / counts) : 0.f;

        float fsum = 0.f;
        #pragma unroll
        for (int c = 0; c < NCLASS; ++c) {
            const float s = sg[c];
            const bool pos = (tmask >> c) & 1u;
            const float pt = pos ? s : 1.f - s;   // |pred|<~5 => no bad cancellation
            const float om = 1.f - pt;
            const float bce = -__logf(pt);
            const float om2 = om * om;
            fsum += om2 * om2 * bce;
        }
        lsum = ALPHA_C * fsum + pfac * (ss - sgsum);
    }

    // Block reduction (same order as before => bitwise identical)
    #pragma unroll
    for (int off = 32; off > 0; off >>= 1)
        lsum += __shfl_xor(lsum, off, 64);
    if (lane == 0) wavesum[tid >> 6] = lsum;
    __syncthreads();

    if (tid == 0) {
        float partial = 0.f;
        #pragma unroll
        for (int w = 0; w < BLOCK / 64; ++w) partial += wavesum[w];
        partials[b] = partial * inv_total;   // plain store; kernel boundary
                                             // guarantees visibility to k2
    }
}

// Kernel 2: one wave collects the 64 partials — identical butterfly order
// to the old in-kernel collector, so the final sum is bitwise identical.
__global__ __launch_bounds__(64) void reduce_kernel(
    const float* __restrict__ partials, float* __restrict__ out, int n)
{
    const int t = threadIdx.x;
    float v = (t < n) ? partials[t] : 0.f;
    #pragma unroll
    for (int off = 32; off > 0; off >>= 1)
        v += __shfl_xor(v, off, 64);
    if (t == 0) out[0] = v;
}

extern "C" void kernel_launch(void* const* d_in, const int* in_sizes, int n_in,
                              void* d_out, int out_size, void* d_ws, size_t ws_size,
                              hipStream_t stream) {
    const float* pred   = (const float*)d_in[0];
    const float* target = (const float*)d_in[1];
    const int*   lines  = (const int*)d_in[2];
    float* out = (float*)d_out;
    float* partials = (float*)d_ws;

    const int n_tokens = in_sizes[2];              // B*S
    const int B = n_tokens / SEQ_LEN;              // 64
    const float inv_total = 1.0f / (float)in_sizes[0];

    fused_kernel<<<B, BLOCK, 0, stream>>>(pred, target, lines, partials, inv_total);
    reduce_kernel<<<1, 64, 0, stream>>>(partials, out, B);
}

// Round 2
// 63.312 us; speedup vs baseline: 1.0059x; 1.0059x over previous
//
#include <hip/hip_runtime.h>
#include <math.h>

#define SEQ_LEN 1024
#define NCLASS 8
#define NLINES 256
#define ALPHA_C 0.01f
#define SPW 0.3f
#define MAGIC 0x5EED5EEDu
#define BLOCK 1024
#define PACK 4096.0f   // cnt*4096 + tsum, both integers; exact below 2^24

// One block per sequence (B=64), 1024 threads (16 waves), 1 token/thread.
// Single dispatch: cross-block reduction via MAGIC-tagged agent-scope slots
// (an extra reduce-kernel dispatch measured +2.4us — more than the spin).
// Phase 1: wave-level SEGMENTED suffix-scan (lines sorted => equal-line runs
// contiguous); only run-head lanes issue LDS atomics, at distinct lines.
// Phase 2 folded into the per-token epilogue (same add order => bitwise
// identical, one barrier + 3KiB LDS cheaper). Global loads hoisted above the
// LDS-init barrier to hide the HBM-cold miss latency (ws poison evicts L3).
__global__ __launch_bounds__(BLOCK) void fused_kernel(
    const float* __restrict__ pred,
    const float* __restrict__ target,
    const int* __restrict__ lines,
    unsigned long long* __restrict__ slots,   // [nblocks] in d_ws
    float* __restrict__ out,
    float inv_total, int nblocks)
{
    __shared__ float binCT[NLINES];    // packed cnt*4096 + sum(target)
    __shared__ float binS[NLINES];     // class-summed sigmoid
    __shared__ float wavesum[BLOCK / 64];

    const int b = blockIdx.x;
    const int tid = threadIdx.x;
    const int lane = tid & 63;
    const int token = b * SEQ_LEN + tid;   // each wave holds 64 consecutive tokens

    // Loads first: poison evicts all of L3, so these are ~900cy cold misses;
    // issuing before the LDS init + barrier overlaps that latency.
    const int l = lines[token];
    const float4 p0 = ((const float4*)pred)[token * 2];
    const float4 p1 = ((const float4*)pred)[token * 2 + 1];
    const float4 t0 = ((const float4*)target)[token * 2];
    const float4 t1 = ((const float4*)target)[token * 2 + 1];

    if (tid < NLINES) {
        binCT[tid] = 0.f;
        binS[tid] = 0.f;
    }
    __syncthreads();

    const float px[NCLASS] = {p0.x, p0.y, p0.z, p0.w, p1.x, p1.y, p1.z, p1.w};

    const float tsum = t0.x + t0.y + t0.z + t0.w + t1.x + t1.y + t1.z + t1.w;
    unsigned tmask = 0;                    // targets are exactly 0/1
    tmask |= (t0.x > 0.5f) ? 1u : 0u;
    tmask |= (t0.y > 0.5f) ? 2u : 0u;
    tmask |= (t0.z > 0.5f) ? 4u : 0u;
    tmask |= (t0.w > 0.5f) ? 8u : 0u;
    tmask |= (t1.x > 0.5f) ? 16u : 0u;
    tmask |= (t1.y > 0.5f) ? 32u : 0u;
    tmask |= (t1.z > 0.5f) ? 64u : 0u;
    tmask |= (t1.w > 0.5f) ? 128u : 0u;

    float sg[NCLASS];
    float sgsum = 0.f;
    #pragma unroll
    for (int c = 0; c < NCLASS; ++c) {
        const float e = __expf(-px[c]);
        const float s = 1.f / (1.f + e);
        sg[c] = s;
        sgsum += s;
    }

    // segmented suffix-scan over the wave; run's first lane gets the run total
    {
        float rp = PACK + tsum;            // cnt=1 packed with tsum
        float rs = sgsum;
        #pragma unroll
        for (int off = 1; off < 64; off <<= 1) {
            const int   ln = __shfl_down(l,  off, 64);
            const float ap = __shfl_down(rp, off, 64);
            const float as = __shfl_down(rs, off, 64);
            const bool same = (lane + off < 64) && (ln == l);
            if (same) { rp += ap; rs += as; }
        }
        const int lprev = __shfl_up(l, 1, 64);
        if ((lane == 0) || (lprev != l)) {
            atomicAdd(&binCT[l], rp);
            atomicAdd(&binS[l], rs);
        }
    }
    __syncthreads();

    // Per-token: 5-wide windowed sums over [l-2, l+2] read straight from the
    // bins (ascending v, same add order as the staged phase-2 => bitwise
    // identical), then the focal loss.
    float lsum;
    {
        const int lo = (l - 2 < 0) ? 0 : l - 2;
        const int hi = (l + 2 > NLINES - 1) ? NLINES - 1 : l + 2;
        float cp = 0.f, ss = 0.f;
        for (int v = lo; v <= hi; ++v) {
            cp += binCT[v];
            ss += binS[v];
        }
        const float cnt = floorf(cp / PACK);
        const float wT  = cp - cnt * PACK;

        const float counts = cnt - 1.f;         // exclude self
        const float ntgt = wT - tsum;           // exclude self
        const bool cond = (counts > 0.f) && (ntgt > 0.f);
        const float pfac = cond ? (SPW * 0.1f / counts) : 0.f;

        float fsum = 0.f;
        #pragma unroll
        for (int c = 0; c < NCLASS; ++c) {
            const float s = sg[c];
            const bool pos = (tmask >> c) & 1u;
            const float pt = pos ? s : 1.f - s;   // |pred|<~5 => no bad cancellation
            const float om = 1.f - pt;
            const float bce = -__logf(pt);
            const float om2 = om * om;
            fsum += om2 * om2 * bce;
        }
        lsum = ALPHA_C * fsum + pfac * (ss - sgsum);
    }

    // Block reduction (same order => bitwise identical)
    #pragma unroll
    for (int off = 32; off > 0; off >>= 1)
        lsum += __shfl_xor(lsum, off, 64);
    if (lane == 0) wavesum[tid >> 6] = lsum;
    __syncthreads();

    if (tid == 0) {
        float partial = 0.f;
        #pragma unroll
        for (int w = 0; w < BLOCK / 64; ++w) partial += wavesum[w];
        partial *= inv_total;
        const unsigned long long payload =
            ((unsigned long long)MAGIC << 32) | (unsigned long long)__float_as_uint(partial);
        __hip_atomic_store(&slots[b], payload, __ATOMIC_RELEASE,
                           __HIP_MEMORY_SCOPE_AGENT);
    }
    // No trailing __syncthreads: the collector's spin on MAGIC provides the
    // ordering, and wave 0 executes tid-0's store before proceeding.

    // block 0, wave 0: collect all partials in parallel and write the result
    if (b == 0 && tid < 64) {
        float v = 0.f;
        if (tid < nblocks) {
            unsigned long long s;
            do {
                s = __hip_atomic_load(&slots[tid], __ATOMIC_ACQUIRE,
                                      __HIP_MEMORY_SCOPE_AGENT);
            } while ((unsigned)(s >> 32) != MAGIC);
            v = __uint_as_float((unsigned)s);
        }
        #pragma unroll
        for (int off = 32; off > 0; off >>= 1)
            v += __shfl_xor(v, off, 64);
        if (tid == 0) out[0] = v;
    }
}

extern "C" void kernel_launch(void* const* d_in, const int* in_sizes, int n_in,
                              void* d_out, int out_size, void* d_ws, size_t ws_size,
                              hipStream_t stream) {
    const float* pred   = (const float*)d_in[0];
    const float* target = (const float*)d_in[1];
    const int*   lines  = (const int*)d_in[2];
    float* out = (float*)d_out;
    unsigned long long* slots = (unsigned long long*)d_ws;

    const int n_tokens = in_sizes[2];              // B*S
    const int B = n_tokens / SEQ_LEN;              // 64
    const float inv_total = 1.0f / (float)in_sizes[0];

    fused_kernel<<<B, BLOCK, 0, stream>>>(pred, target, lines, slots, out,
                                          inv_total, B);
}

// Round 3
// 61.167 us; speedup vs baseline: 1.0411x; 1.0351x over previous
//
#include <hip/hip_runtime.h>
#include <math.h>

#define SEQ_LEN 1024
#define NCLASS 8
#define NLINES 256
#define ALPHA_C 0.01f
#define SPW 0.3f
#define MAGIC 0x5EED5EEDu
#define BLOCK 1024
#define PACK 4096.0f   // cnt*4096 + tsum, both integers; max 64*4096+512 < 2^24 (exact)

// One block per sequence (B=64), 1024 threads (16 waves), 1 token/thread.
// Phase 1: wave-level SEGMENTED suffix-scan (lines sorted => equal-line runs
// contiguous); only run-head lanes issue LDS atomics, at distinct lines.
// cnt and sum(target) are small integers -> packed into ONE float channel
// (exact below 2^24), so the scan moves 3 channels instead of 4.
// NOTE (R1/R2 post-mortems): 2-kernel split = +2.4us (extra dispatch beats
// the spin cost); bundled tweaks (folded phase-2 / hoisted loads / dropped
// trailing barrier) = +2.0us vs this exact source. This is the best
// measured configuration (61.3 / 61.8 us in two sessions).
__global__ __launch_bounds__(BLOCK) void fused_kernel(
    const float* __restrict__ pred,
    const float* __restrict__ target,
    const int* __restrict__ lines,
    unsigned long long* __restrict__ slots,   // [nblocks] in d_ws
    float* __restrict__ out,
    float inv_total, int nblocks)
{
    __shared__ float binCT[NLINES];    // packed cnt*4096 + sum(target)
    __shared__ float binS[NLINES];     // class-summed sigmoid
    __shared__ float wCnt[NLINES];
    __shared__ float wT[NLINES];
    __shared__ float wS[NLINES];
    __shared__ float wavesum[BLOCK / 64];

    const int b = blockIdx.x;
    const int tid = threadIdx.x;
    const int lane = tid & 63;

    if (tid < NLINES) {
        binCT[tid] = 0.f;
        binS[tid] = 0.f;
    }
    __syncthreads();

    const int token = b * SEQ_LEN + tid;   // each wave holds 64 consecutive tokens
    const int l = lines[token];
    const float4 p0 = ((const float4*)pred)[token * 2];
    const float4 p1 = ((const float4*)pred)[token * 2 + 1];
    const float4 t0 = ((const float4*)target)[token * 2];
    const float4 t1 = ((const float4*)target)[token * 2 + 1];
    const float px[NCLASS] = {p0.x, p0.y, p0.z, p0.w, p1.x, p1.y, p1.z, p1.w};

    const float tsum = t0.x + t0.y + t0.z + t0.w + t1.x + t1.y + t1.z + t1.w;
    unsigned tmask = 0;                    // targets are exactly 0/1
    tmask |= (t0.x > 0.5f) ? 1u : 0u;
    tmask |= (t0.y > 0.5f) ? 2u : 0u;
    tmask |= (t0.z > 0.5f) ? 4u : 0u;
    tmask |= (t0.w > 0.5f) ? 8u : 0u;
    tmask |= (t1.x > 0.5f) ? 16u : 0u;
    tmask |= (t1.y > 0.5f) ? 32u : 0u;
    tmask |= (t1.z > 0.5f) ? 64u : 0u;
    tmask |= (t1.w > 0.5f) ? 128u : 0u;

    float sg[NCLASS];
    float sgsum = 0.f;
    #pragma unroll
    for (int c = 0; c < NCLASS; ++c) {
        const float e = __expf(-px[c]);
        const float s = 1.f / (1.f + e);
        sg[c] = s;
        sgsum += s;
    }

    // segmented suffix-scan over the wave; run's first lane gets the run total
    {
        float rp = PACK + tsum;            // cnt=1 packed with tsum
        float rs = sgsum;
        #pragma unroll
        for (int off = 1; off < 64; off <<= 1) {
            const int   ln = __shfl_down(l,  off, 64);
            const float ap = __shfl_down(rp, off, 64);
            const float as = __shfl_down(rs, off, 64);
            const bool same = (lane + off < 64) && (ln == l);
            if (same) { rp += ap; rs += as; }
        }
        const int lprev = __shfl_up(l, 1, 64);
        if ((lane == 0) || (lprev != l)) {
            atomicAdd(&binCT[l], rp);
            atomicAdd(&binS[l], rs);
        }
    }
    __syncthreads();

    // Phase 2: 5-wide windowed sums over line values [v-2, v+2]
    if (tid < NLINES) {
        const int lo = (tid - 2 < 0) ? 0 : tid - 2;
        const int hi = (tid + 2 > NLINES - 1) ? NLINES - 1 : tid + 2;
        float cp = 0.f, ss = 0.f;
        for (int v = lo; v <= hi; ++v) {
            cp += binCT[v];
            ss += binS[v];
        }
        const float cnt = floorf(cp / PACK);
        wCnt[tid] = cnt;
        wT[tid] = cp - cnt * PACK;
        wS[tid] = ss;
    }
    __syncthreads();

    // Phase 3: per-token loss (log only; sg from registers)
    float lsum;
    {
        const float counts = wCnt[l] - 1.f;     // exclude self
        const float ntgt = wT[l] - tsum;        // exclude self
        const bool cond = (counts > 0.f) && (ntgt > 0.f);
        const float pfac = cond ? (SPW * 0.1f / counts) : 0.f;

        float fsum = 0.f;
        #pragma unroll
        for (int c = 0; c < NCLASS; ++c) {
            const float s = sg[c];
            const bool pos = (tmask >> c) & 1u;
            const float pt = pos ? s : 1.f - s;   // |pred|<~5 => no bad cancellation
            const float om = 1.f - pt;
            const float bce = -__logf(pt);
            const float om2 = om * om;
            fsum += om2 * om2 * bce;
        }
        lsum = ALPHA_C * fsum + pfac * (wS[l] - sgsum);
    }

    // Phase 4: block reduction
    #pragma unroll
    for (int off = 32; off > 0; off >>= 1)
        lsum += __shfl_xor(lsum, off, 64);
    if (lane == 0) wavesum[tid >> 6] = lsum;
    __syncthreads();

    if (tid == 0) {
        float partial = 0.f;
        #pragma unroll
        for (int w = 0; w < BLOCK / 64; ++w) partial += wavesum[w];
        partial *= inv_total;
        const unsigned long long payload =
            ((unsigned long long)MAGIC << 32) | (unsigned long long)__float_as_uint(partial);
        __hip_atomic_store(&slots[b], payload, __ATOMIC_RELEASE,
                           __HIP_MEMORY_SCOPE_AGENT);
    }
    __syncthreads();

    // block 0, wave 0: collect all partials in parallel and write the result
    if (b == 0 && tid < 64) {
        float v = 0.f;
        if (tid < nblocks) {
            unsigned long long s;
            do {
                s = __hip_atomic_load(&slots[tid], __ATOMIC_ACQUIRE,
                                      __HIP_MEMORY_SCOPE_AGENT);
            } while ((unsigned)(s >> 32) != MAGIC);
            v = __uint_as_float((unsigned)s);
        }
        #pragma unroll
        for (int off = 32; off > 0; off >>= 1)
            v += __shfl_xor(v, off, 64);
        if (tid == 0) out[0] = v;
    }
}

extern "C" void kernel_launch(void* const* d_in, const int* in_sizes, int n_in,
                              void* d_out, int out_size, void* d_ws, size_t ws_size,
                              hipStream_t stream) {
    const float* pred   = (const float*)d_in[0];
    const float* target = (const float*)d_in[1];
    const int*   lines  = (const int*)d_in[2];
    float* out = (float*)d_out;
    unsigned long long* slots = (unsigned long long*)d_ws;

    const int n_tokens = in_sizes[2];              // B*S
    const int B = n_tokens / SEQ_LEN;              // 64
    const float inv_total = 1.0f / (float)in_sizes[0];

    fused_kernel<<<B, BLOCK, 0, stream>>>(pred, target, lines, slots, out,
                                          inv_total, B);
}